// Round 1
// baseline (296.434 us; speedup 1.0000x reference)
//
#include <hip/hip_runtime.h>

#define NUM_BINS 15
#define NBLOCKS 1024
#define NTHREADS 256
#define NCOMP (3 * NUM_BINS)   // 45: cnt[15], conf[15], acc[15]

// Kernel 1: per-thread register histograms -> wave shuffle reduce -> block
// partials into ws laid out comp-major: ws[c * NBLOCKS + blockIdx.x].
__global__ __launch_bounds__(NTHREADS) void ece_partial(
    const float* __restrict__ probs, const int* __restrict__ labels,
    float* __restrict__ ws, int n4)
{
    float cnt[NUM_BINS], conf[NUM_BINS], acc[NUM_BINS];
#pragma unroll
    for (int b = 0; b < NUM_BINS; ++b) { cnt[b] = 0.f; conf[b] = 0.f; acc[b] = 0.f; }

    const float4* __restrict__ p4 = (const float4*)probs;
    const int4*   __restrict__ l4 = (const int4*)labels;

    const int stride = gridDim.x * blockDim.x;
    for (int i = blockIdx.x * blockDim.x + threadIdx.x; i < n4; i += stride) {
        float4 p = p4[i];
        int4   l = l4[i];
        float ps[4] = {p.x, p.y, p.z, p.w};
        int   ls[4] = {l.x, l.y, l.z, l.w};
#pragma unroll
        for (int e = 0; e < 4; ++e) {
            float pv = ps[e];
            float lf = (float)ls[e];
            // bin = clip(ceil(p*15)-1, 0, 14); invalid (p<=0 || p>1) matches no bin
            int bin = (int)ceilf(pv * 15.0f) - 1;
            bin = min(max(bin, 0), NUM_BINS - 1);
            if (!((pv > 0.0f) && (pv <= 1.0f))) bin = -1;
#pragma unroll
            for (int b = 0; b < NUM_BINS; ++b) {
                float w = (bin == b) ? 1.0f : 0.0f;
                cnt[b]  += w;
                conf[b]  = fmaf(w, pv, conf[b]);
                acc[b]   = fmaf(w, lf, acc[b]);
            }
        }
    }

    // wave-level butterfly reduce (wave = 64 lanes)
#pragma unroll
    for (int b = 0; b < NUM_BINS; ++b) {
#pragma unroll
        for (int off = 32; off; off >>= 1) {
            cnt[b]  += __shfl_down(cnt[b],  off);
            conf[b] += __shfl_down(conf[b], off);
            acc[b]  += __shfl_down(acc[b],  off);
        }
    }

    __shared__ float red[NTHREADS / 64][NCOMP];
    const int wave = threadIdx.x >> 6;
    const int lane = threadIdx.x & 63;
    if (lane == 0) {
#pragma unroll
        for (int b = 0; b < NUM_BINS; ++b) {
            red[wave][b]                = cnt[b];
            red[wave][NUM_BINS + b]     = conf[b];
            red[wave][2 * NUM_BINS + b] = acc[b];
        }
    }
    __syncthreads();
    if (threadIdx.x < NCOMP) {
        float s = 0.f;
#pragma unroll
        for (int w = 0; w < NTHREADS / 64; ++w) s += red[w][threadIdx.x];
        ws[threadIdx.x * gridDim.x + blockIdx.x] = s;
    }
}

// Kernel 2: one block reduces the [45][NBLOCKS] partials and emits ECE.
__global__ __launch_bounds__(1024) void ece_final(
    const float* __restrict__ ws, float* __restrict__ out, int nblocks, float n)
{
    __shared__ float sums[NCOMP];
    const int wave   = threadIdx.x >> 6;
    const int lane   = threadIdx.x & 63;
    const int nwaves = blockDim.x >> 6;

    for (int c = wave; c < NCOMP; c += nwaves) {
        float s = 0.f;
        for (int i = lane; i < nblocks; i += 64) s += ws[c * nblocks + i];
#pragma unroll
        for (int off = 32; off; off >>= 1) s += __shfl_down(s, off);
        if (lane == 0) sums[c] = s;
    }
    __syncthreads();

    if (threadIdx.x == 0) {
        float ece = 0.f;
#pragma unroll
        for (int b = 0; b < NUM_BINS; ++b) {
            float c  = sums[b];
            float cf = sums[NUM_BINS + b];
            float ac = sums[2 * NUM_BINS + b];
            float denom = fmaxf(c, 1.0f);
            ece += (c / n) * fabsf(ac / denom - cf / denom);
        }
        out[0] = ece;
    }
}

extern "C" void kernel_launch(void* const* d_in, const int* in_sizes, int n_in,
                              void* d_out, int out_size, void* d_ws, size_t ws_size,
                              hipStream_t stream)
{
    const float* probs  = (const float*)d_in[0];
    const int*   labels = (const int*)d_in[1];
    float*       out    = (float*)d_out;
    float*       ws     = (float*)d_ws;   // needs 45 * NBLOCKS * 4 = 184,320 B

    const int n  = in_sizes[0];
    const int n4 = n / 4;   // N = 2^25, divisible by 4

    ece_partial<<<NBLOCKS, NTHREADS, 0, stream>>>(probs, labels, ws, n4);
    ece_final<<<1, 1024, 0, stream>>>(ws, out, NBLOCKS, (float)n);
}